// Round 2
// baseline (669.492 us; speedup 1.0000x reference)
//
#include <hip/hip_runtime.h>
#include <math.h>

#define S_TOK 2048
#define NEXP  8
#define DDIM  768
#define HDIM  3072
#define KSEL  4096   // S * CAPACITY
#define NTILES_MAX 72

__device__ __forceinline__ float gelu_tanh(float v) {
  float u = 0.7978845608028654f * (v + 0.044715f * v * v * v);
  return 0.5f * v * (1.0f + tanhf(u));
}

__global__ __launch_bounds__(256) void zero_kernel(float* __restrict__ p, int n) {
  int i = blockIdx.x * 256 + threadIdx.x;
  if (i < n) p[i] = 0.f;
}

// ---------------- K1: gating (logits + softmax) ----------------
__global__ __launch_bounds__(256) void gate_kernel(
    const float* __restrict__ x, const float* __restrict__ gw,
    float* __restrict__ scores)
{
  int tid  = threadIdx.x;
  int lane = tid & 63;
  int wid  = tid >> 6;
  int token = blockIdx.x * 4 + wid;
  const float* xr = x + (size_t)token * DDIM;

  float acc[NEXP];
#pragma unroll
  for (int e = 0; e < NEXP; ++e) acc[e] = 0.f;

  for (int d = lane; d < DDIM; d += 64) {
    float xv = xr[d];
#pragma unroll
    for (int e = 0; e < NEXP; ++e) acc[e] += xv * gw[e * DDIM + d];
  }
#pragma unroll
  for (int e = 0; e < NEXP; ++e) {
    for (int off = 32; off; off >>= 1) acc[e] += __shfl_down(acc[e], off, 64);
  }
  if (lane == 0) {
    float m = acc[0];
#pragma unroll
    for (int e = 1; e < NEXP; ++e) m = fmaxf(m, acc[e]);
    float p[NEXP], s = 0.f;
#pragma unroll
    for (int e = 0; e < NEXP; ++e) { p[e] = expf(acc[e] - m); s += p[e]; }
    float inv = 1.0f / s;
#pragma unroll
    for (int e = 0; e < NEXP; ++e) scores[e * S_TOK + token] = p[e] * inv;
  }
}

// ---------------- K2: exact global top-k selection + tile map ----------------
__device__ unsigned block_scan_excl(unsigned v, volatile unsigned* wsum) {
  int tid = threadIdx.x, lane = tid & 63, wid = tid >> 6;
  __syncthreads();               // protect wsum reuse across calls
  unsigned x = v;
#pragma unroll
  for (int off = 1; off < 64; off <<= 1) {
    unsigned t = __shfl_up(x, off, 64);
    if (lane >= off) x += t;
  }
  if (lane == 63) wsum[wid] = x;
  __syncthreads();
  if (tid < 64) {
    unsigned w = (lane < 16) ? wsum[lane] : 0u;
#pragma unroll
    for (int off = 1; off < 16; off <<= 1) {
      unsigned t = __shfl_up(w, off, 64);
      if (lane >= off) w += t;
    }
    if (lane < 16) wsum[lane] = w;   // inclusive over waves
  }
  __syncthreads();
  unsigned woff = (wid > 0) ? wsum[wid - 1] : 0u;
  return woff + (x - v);             // exclusive prefix
}

__global__ __launch_bounds__(1024) void select_kernel(
    const float* __restrict__ scores,
    int* __restrict__ tokenlist, float* __restrict__ slotgate,
    int* __restrict__ offsets, int* __restrict__ tilemap)
{
  __shared__ unsigned cnt;
  __shared__ unsigned wsum[16];
  __shared__ int soff[8];
  int tid = threadIdx.x;
  int base = tid * 16;

  float sv[16]; unsigned key[16];
#pragma unroll
  for (int j = 0; j < 16; ++j) {
    sv[j] = scores[base + j];
    key[j] = __float_as_uint(sv[j]);   // scores > 0 -> bits order-preserving
  }

  // binary search: largest t with count(key >= t) >= KSEL
  unsigned lo = 0, hi = 0x3F800000u;   // scores < 1.0
  while (lo < hi) {
    unsigned mid = lo + ((hi - lo + 1) >> 1);
    if (tid == 0) cnt = 0;
    __syncthreads();
    unsigned c = 0;
#pragma unroll
    for (int j = 0; j < 16; ++j) c += (key[j] >= mid) ? 1u : 0u;
    for (int off = 32; off; off >>= 1) c += __shfl_down(c, off, 64);
    if ((tid & 63) == 0) atomicAdd(&cnt, c);
    __syncthreads();
    unsigned tot = cnt;
    __syncthreads();
    if (tot >= (unsigned)KSEL) lo = mid; else hi = mid - 1;
  }
  unsigned V = lo;

  // count strictly greater
  if (tid == 0) cnt = 0;
  __syncthreads();
  {
    unsigned c = 0;
#pragma unroll
    for (int j = 0; j < 16; ++j) c += (key[j] > V) ? 1u : 0u;
    for (int off = 32; off; off >>= 1) c += __shfl_down(c, off, 64);
    if ((tid & 63) == 0) atomicAdd(&cnt, c);
  }
  __syncthreads();
  int need = KSEL - (int)cnt;   // ties to take, ascending flat-index order
  __syncthreads();

  unsigned tloc = 0;
#pragma unroll
  for (int j = 0; j < 16; ++j) tloc += (key[j] == V) ? 1u : 0u;
  unsigned texcl = block_scan_excl(tloc, wsum);

  unsigned selmask = 0, sloc = 0, trun = texcl;
#pragma unroll
  for (int j = 0; j < 16; ++j) {
    bool f;
    if (key[j] > V) f = true;
    else if (key[j] == V) { f = ((int)trun < need); ++trun; }
    else f = false;
    if (f) { selmask |= (1u << j); ++sloc; }
  }
  unsigned sexcl = block_scan_excl(sloc, wsum);

  // expert e starts at flat index e*2048 == thread e*128
  if ((tid & 127) == 0) soff[tid >> 7] = (int)sexcl;
  __syncthreads();
  if (tid == 0) {
    int nt = 0;
#pragma unroll
    for (int e = 0; e < NEXP; ++e) {
      offsets[e] = soff[e];
      int rows = ((e == NEXP - 1) ? KSEL : soff[e + 1]) - soff[e];
      int t = (rows + 63) >> 6;
      for (int i = 0; i < t; ++i) tilemap[nt++] = (e << 16) | i;
    }
    offsets[NEXP] = KSEL;
    for (int i = nt; i < NTILES_MAX; ++i) tilemap[i] = -1;
  }

  unsigned p = sexcl;
#pragma unroll
  for (int j = 0; j < 16; ++j) {
    int i = base + j;
    if (selmask & (1u << j)) {
      tokenlist[p] = i & (S_TOK - 1);
      slotgate[p] = sv[j];
      ++p;
    }
  }
}

// ---------------- K3/K4: grouped GEMM via tile map, 64x64 tile ----------------
// MODE 1: A = x gathered via tokenlist -> hbuf[chunk-local] = gelu(A@W1 + b1)
// MODE 2: A = hbuf[chunk-local]; y[token] += gate * (A@W2 + b2)  (atomic)
template <int MODE>
__global__ __launch_bounds__(256) void moe_gemm(
    const float* __restrict__ A, const float* __restrict__ W,
    const float* __restrict__ bias, float* __restrict__ out,
    const int* __restrict__ offsets, const int* __restrict__ tokenlist,
    const float* __restrict__ slotgate, const int* __restrict__ tilemap,
    int chunk_base, int K, int N)
{
  const int tinfo = tilemap[chunk_base + blockIdx.y];
  if (tinfo < 0) return;
  const int e = tinfo >> 16;
  const int tloc = tinfo & 0xffff;
  const int r0 = offsets[e];
  const int rows = offsets[e + 1] - r0;
  const int rowbase = tloc << 6;
  int vr = rows - rowbase; if (vr > 64) vr = 64;   // valid rows in tile (>=1)
  const int colbase = blockIdx.x * 64;
  const int lbuf = (int)blockIdx.y << 6;           // chunk-local hbuf row base

  const float* Wp = W + (size_t)e * K * N + colbase;
  const float* bp = bias + (size_t)e * N + colbase;

  __shared__ float As[16][72];   // [k][row]
  __shared__ float Bs[16][72];   // [k][col]

  const int tid = threadIdx.x;
  const int tx = tid & 15, ty = tid >> 4;

  const int lrow = tid >> 2;
  const int lkk  = (tid & 3) * 4;
  const int crow = (lrow < vr) ? lrow : (vr - 1);
  const float* Arow;
  if (MODE == 1) {
    int token = tokenlist[r0 + rowbase + crow];
    Arow = A + (size_t)token * K;
  } else {
    Arow = A + (size_t)(lbuf + crow) * K;
  }

  const int bk = tid >> 4;
  const int bn = (tid & 15) * 4;

  float c[4][4] = {{0.f}};

  for (int k0 = 0; k0 < K; k0 += 16) {
    float4 av = *(const float4*)(Arow + k0 + lkk);
    As[lkk + 0][lrow] = av.x;
    As[lkk + 1][lrow] = av.y;
    As[lkk + 2][lrow] = av.z;
    As[lkk + 3][lrow] = av.w;
    *(float4*)&Bs[bk][bn] = *(const float4*)(Wp + (size_t)(k0 + bk) * N + bn);
    __syncthreads();
#pragma unroll
    for (int k = 0; k < 16; ++k) {
      float4 a = *(const float4*)&As[k][ty * 4];
      float4 b = *(const float4*)&Bs[k][tx * 4];
      float ar[4] = {a.x, a.y, a.z, a.w};
      float br[4] = {b.x, b.y, b.z, b.w};
#pragma unroll
      for (int i = 0; i < 4; ++i)
#pragma unroll
        for (int j = 0; j < 4; ++j)
          c[i][j] = fmaf(ar[i], br[j], c[i][j]);
    }
    __syncthreads();
  }

#pragma unroll
  for (int i = 0; i < 4; ++i) {
    int rr = ty * 4 + i;
    if (rr >= vr) continue;
    if (MODE == 1) {
      float v[4];
#pragma unroll
      for (int j = 0; j < 4; ++j) v[j] = gelu_tanh(c[i][j] + bp[tx * 4 + j]);
      float* op = out + (size_t)(lbuf + rr) * N + colbase + tx * 4;
      *(float4*)op = make_float4(v[0], v[1], v[2], v[3]);
    } else {
      int gi = r0 + rowbase + rr;
      float g = slotgate[gi];
      int token = tokenlist[gi];
      float* yp = out + (size_t)token * N + colbase + tx * 4;
#pragma unroll
      for (int j = 0; j < 4; ++j)
        atomicAdd(&yp[j], g * (c[i][j] + bp[tx * 4 + j]));
    }
  }
}

extern "C" void kernel_launch(void* const* d_in, const int* in_sizes, int n_in,
                              void* d_out, int out_size, void* d_ws, size_t ws_size,
                              hipStream_t stream) {
  const float* x  = (const float*)d_in[0];
  const float* gw = (const float*)d_in[1];
  const float* w1 = (const float*)d_in[2];
  const float* b1 = (const float*)d_in[3];
  const float* w2 = (const float*)d_in[4];
  const float* b2 = (const float*)d_in[5];
  float* y = (float*)d_out;

  char* ws = (char*)d_ws;
  float* scores    = (float*)(ws);                    // 64 KB
  int*   tokenlist = (int*)(ws + (64 << 10));         // 16 KB
  float* slotgate  = (float*)(ws + (80 << 10));       // 16 KB
  int*   offsets   = (int*)(ws + (96 << 10));         // 9 ints
  int*   tilemap   = (int*)(ws + (96 << 10) + 256);   // 72 ints
  float* hbuf      = (float*)(ws + (128 << 10));      // chunked

  const size_t tile_bytes = (size_t)64 * HDIM * 4;    // 768 KB per tile
  size_t avail = (ws_size > (size_t)(128 << 10)) ? ws_size - (size_t)(128 << 10) : 0;
  int tchunk = (int)(avail / tile_bytes);
  if (tchunk > NTILES_MAX) tchunk = NTILES_MAX;
  if (tchunk < 1) tchunk = 1;

  zero_kernel<<<(out_size + 255) / 256, 256, 0, stream>>>(y, out_size);
  gate_kernel<<<S_TOK / 4, 256, 0, stream>>>(x, gw, scores);
  select_kernel<<<1, 1024, 0, stream>>>(scores, tokenlist, slotgate, offsets, tilemap);

  for (int t0 = 0; t0 < NTILES_MAX; t0 += tchunk) {
    int tc = NTILES_MAX - t0; if (tc > tchunk) tc = tchunk;
    dim3 g1(HDIM / 64, tc);
    moe_gemm<1><<<g1, 256, 0, stream>>>(x, w1, b1, hbuf, offsets, tokenlist,
                                        slotgate, tilemap, t0, DDIM, HDIM);
    dim3 g2(DDIM / 64, tc);
    moe_gemm<2><<<g2, 256, 0, stream>>>(hbuf, w2, b2, y, offsets, tokenlist,
                                        slotgate, tilemap, t0, HDIM, DDIM);
  }
}

// Round 3
// 204.127 us; speedup vs baseline: 3.2798x; 3.2798x over previous
//
#include <hip/hip_runtime.h>
#include <math.h>

#define S_TOK 2048
#define NEXP  8
#define DDIM  768
#define HDIM  3072
#define KSEL  4096   // S * CAPACITY
#define NT_MAX 40    // sum_e ceil(rows_e/128) <= 4096/128 + 8

typedef __attribute__((ext_vector_type(8))) short short8;
typedef __attribute__((ext_vector_type(4))) float f32x4;

__device__ __forceinline__ unsigned short f2bf(float f) {
  unsigned u = __float_as_uint(f);
  u += 0x7fffu + ((u >> 16) & 1u);   // round-to-nearest-even
  return (unsigned short)(u >> 16);
}

__device__ __forceinline__ float gelu_fast(float v) {
  float u = 0.7978845608028654f * (v + 0.044715f * v * v * v);
  float t = __expf(-2.0f * fabsf(u));
  float th = (1.0f - t) / (1.0f + t);
  th = copysignf(th, u);
  return 0.5f * v * (1.0f + th);
}

__global__ __launch_bounds__(256) void zero_kernel(float* __restrict__ p, int n) {
  int i = blockIdx.x * 256 + threadIdx.x;
  if (i < n) p[i] = 0.f;
}

__global__ __launch_bounds__(256) void convx_kernel(const float* __restrict__ x,
                                                    short* __restrict__ xb) {
  int i = (blockIdx.x * 256 + threadIdx.x) * 8;
  float4 a = *(const float4*)(x + i);
  float4 b = *(const float4*)(x + i + 4);
  short8 v;
  v[0] = (short)f2bf(a.x); v[1] = (short)f2bf(a.y);
  v[2] = (short)f2bf(a.z); v[3] = (short)f2bf(a.w);
  v[4] = (short)f2bf(b.x); v[5] = (short)f2bf(b.y);
  v[6] = (short)f2bf(b.z); v[7] = (short)f2bf(b.w);
  *(short8*)(xb + i) = v;
}

// ---------------- K1: gating (logits + softmax), exact fp32 ----------------
__global__ __launch_bounds__(256) void gate_kernel(
    const float* __restrict__ x, const float* __restrict__ gw,
    float* __restrict__ scores)
{
  int tid  = threadIdx.x;
  int lane = tid & 63;
  int wid  = tid >> 6;
  int token = blockIdx.x * 4 + wid;
  const float* xr = x + (size_t)token * DDIM;

  float acc[NEXP];
#pragma unroll
  for (int e = 0; e < NEXP; ++e) acc[e] = 0.f;

  for (int d = lane; d < DDIM; d += 64) {
    float xv = xr[d];
#pragma unroll
    for (int e = 0; e < NEXP; ++e) acc[e] += xv * gw[e * DDIM + d];
  }
#pragma unroll
  for (int e = 0; e < NEXP; ++e) {
    for (int off = 32; off; off >>= 1) acc[e] += __shfl_down(acc[e], off, 64);
  }
  if (lane == 0) {
    float m = acc[0];
#pragma unroll
    for (int e = 1; e < NEXP; ++e) m = fmaxf(m, acc[e]);
    float p[NEXP], s = 0.f;
#pragma unroll
    for (int e = 0; e < NEXP; ++e) { p[e] = expf(acc[e] - m); s += p[e]; }
    float inv = 1.0f / s;
#pragma unroll
    for (int e = 0; e < NEXP; ++e) scores[e * S_TOK + token] = p[e] * inv;
  }
}

// ---------------- K2: exact global top-k selection + tile map ----------------
__device__ unsigned block_scan_excl(unsigned v, volatile unsigned* wsum) {
  int tid = threadIdx.x, lane = tid & 63, wid = tid >> 6;
  __syncthreads();
  unsigned x = v;
#pragma unroll
  for (int off = 1; off < 64; off <<= 1) {
    unsigned t = __shfl_up(x, off, 64);
    if (lane >= off) x += t;
  }
  if (lane == 63) wsum[wid] = x;
  __syncthreads();
  if (tid < 64) {
    unsigned w = (lane < 16) ? wsum[lane] : 0u;
#pragma unroll
    for (int off = 1; off < 16; off <<= 1) {
      unsigned t = __shfl_up(w, off, 64);
      if (lane >= off) w += t;
    }
    if (lane < 16) wsum[lane] = w;
  }
  __syncthreads();
  unsigned woff = (wid > 0) ? wsum[wid - 1] : 0u;
  return woff + (x - v);
}

__global__ __launch_bounds__(1024) void select_kernel(
    const float* __restrict__ scores,
    int* __restrict__ tokenlist, float* __restrict__ slotgate,
    int* __restrict__ offsets, int* __restrict__ tilemap)
{
  __shared__ unsigned cnt;
  __shared__ unsigned wsum[16];
  __shared__ int soff[8];
  int tid = threadIdx.x;
  int base = tid * 16;

  float sv[16]; unsigned key[16];
#pragma unroll
  for (int j = 0; j < 16; ++j) {
    sv[j] = scores[base + j];
    key[j] = __float_as_uint(sv[j]);
  }

  unsigned lo = 0, hi = 0x3F800000u;
  while (lo < hi) {
    unsigned mid = lo + ((hi - lo + 1) >> 1);
    if (tid == 0) cnt = 0;
    __syncthreads();
    unsigned c = 0;
#pragma unroll
    for (int j = 0; j < 16; ++j) c += (key[j] >= mid) ? 1u : 0u;
    for (int off = 32; off; off >>= 1) c += __shfl_down(c, off, 64);
    if ((tid & 63) == 0) atomicAdd(&cnt, c);
    __syncthreads();
    unsigned tot = cnt;
    __syncthreads();
    if (tot >= (unsigned)KSEL) lo = mid; else hi = mid - 1;
  }
  unsigned V = lo;

  if (tid == 0) cnt = 0;
  __syncthreads();
  {
    unsigned c = 0;
#pragma unroll
    for (int j = 0; j < 16; ++j) c += (key[j] > V) ? 1u : 0u;
    for (int off = 32; off; off >>= 1) c += __shfl_down(c, off, 64);
    if ((tid & 63) == 0) atomicAdd(&cnt, c);
  }
  __syncthreads();
  int need = KSEL - (int)cnt;
  __syncthreads();

  unsigned tloc = 0;
#pragma unroll
  for (int j = 0; j < 16; ++j) tloc += (key[j] == V) ? 1u : 0u;
  unsigned texcl = block_scan_excl(tloc, wsum);

  unsigned selmask = 0, sloc = 0, trun = texcl;
#pragma unroll
  for (int j = 0; j < 16; ++j) {
    bool f;
    if (key[j] > V) f = true;
    else if (key[j] == V) { f = ((int)trun < need); ++trun; }
    else f = false;
    if (f) { selmask |= (1u << j); ++sloc; }
  }
  unsigned sexcl = block_scan_excl(sloc, wsum);

  if ((tid & 127) == 0) soff[tid >> 7] = (int)sexcl;
  __syncthreads();
  if (tid == 0) {
    int nt = 0;
#pragma unroll
    for (int e = 0; e < NEXP; ++e) {
      offsets[e] = soff[e];
      int rows = ((e == NEXP - 1) ? KSEL : soff[e + 1]) - soff[e];
      int t = (rows + 127) >> 7;
      for (int i = 0; i < t; ++i) tilemap[nt++] = (e << 16) | i;
    }
    offsets[NEXP] = KSEL;
    for (int i = nt; i < NT_MAX; ++i) tilemap[i] = -1;
  }

  unsigned p = sexcl;
#pragma unroll
  for (int j = 0; j < 16; ++j) {
    int i = base + j;
    if (selmask & (1u << j)) {
      tokenlist[p] = i & (S_TOK - 1);
      slotgate[p] = sv[j];
      ++p;
    }
  }
}

// ---------------- K3/K4: bf16 MFMA grouped GEMM, 128x128 tile, BK=32 ----------------
// MODE 1: A = xbf gathered via tokenlist (K=768);  hbuf = gelu(A@W1 + b1) (bf16)
// MODE 2: A = hbuf chunk-local (K=3072, split z);  y[token] += gate*(A@W2 + b2) atomically
template <int MODE>
__global__ __launch_bounds__(256) void moe_mfma(
    const short* __restrict__ Abase, const float* __restrict__ W,
    const float* __restrict__ bias, void* __restrict__ outp,
    const int* __restrict__ offsets, const int* __restrict__ tokenlist,
    const float* __restrict__ slotgate, const int* __restrict__ tilemap,
    int chunk_base, int K, int N, int klen)
{
  const int tinfo = tilemap[chunk_base + blockIdx.y];
  if (tinfo < 0) return;
  const int e = tinfo >> 16;
  const int tloc = tinfo & 0xffff;
  const int r0 = offsets[e];
  const int rows = offsets[e + 1] - r0;
  const int rowbase = tloc << 7;
  int vr = rows - rowbase; if (vr > 128) vr = 128;
  const int colbase = (int)blockIdx.x << 7;
  const int lbuf = (int)blockIdx.y << 7;
  const int split = (int)blockIdx.z;
  const int kb = split * klen;

  __shared__ short Ab[128 * 40];
  __shared__ short Bb[128 * 40];

  const int tid = threadIdx.x;
  const int lane = tid & 63;
  const int wid = tid >> 6;
  const int wr = (wid >> 1) << 6;   // wave row offset (0/64)
  const int wc = (wid & 1) << 6;    // wave col offset (0/64)
  const int l15 = lane & 15;
  const int lq = lane >> 4;         // 0..3

  // A staging: thread -> row ar=tid>>1, k-half ak=(tid&1)*16
  const int ar = tid >> 1;
  const int ak = (tid & 1) << 4;
  const short* arow;
  {
    int cr = (ar < vr) ? ar : (vr - 1);
    if (MODE == 1) arow = Abase + (size_t)tokenlist[r0 + rowbase + cr] * DDIM;
    else           arow = Abase + (size_t)(lbuf + cr) * HDIM;
  }
  // B staging: thread -> col bn=tid&127, k-half bk=(tid>>7)*16 (column-strided fp32)
  const int bn = tid & 127;
  const int bk = (tid >> 7) << 4;
  const float* wcol = W + (size_t)e * K * N + colbase + bn;

  f32x4 acc[4][4];
#pragma unroll
  for (int i = 0; i < 4; ++i)
#pragma unroll
    for (int j = 0; j < 4; ++j) acc[i][j] = (f32x4){0.f, 0.f, 0.f, 0.f};

  short8 av0, av1;
  float bw[16];
  {
    const short* ap = arow + kb + ak;
    av0 = *(const short8*)(ap);
    av1 = *(const short8*)(ap + 8);
    const float* wp = wcol + (size_t)(kb + bk) * N;
#pragma unroll
    for (int j = 0; j < 16; ++j) bw[j] = wp[(size_t)j * N];
  }

  for (int k0 = 0; k0 < klen; k0 += 32) {
    __syncthreads();
    *(short8*)&Ab[ar * 40 + ak] = av0;
    *(short8*)&Ab[ar * 40 + ak + 8] = av1;
    {
      short8 b0, b1;
#pragma unroll
      for (int j = 0; j < 8; ++j) {
        b0[j] = (short)f2bf(bw[j]);
        b1[j] = (short)f2bf(bw[j + 8]);
      }
      *(short8*)&Bb[bn * 40 + bk] = b0;
      *(short8*)&Bb[bn * 40 + bk + 8] = b1;
    }
    __syncthreads();
    if (k0 + 32 < klen) {
      const short* ap = arow + kb + k0 + 32 + ak;
      av0 = *(const short8*)(ap);
      av1 = *(const short8*)(ap + 8);
      const float* wp = wcol + (size_t)(kb + k0 + 32 + bk) * N;
#pragma unroll
      for (int j = 0; j < 16; ++j) bw[j] = wp[(size_t)j * N];
    }
    short8 af[4], bfr[4];
#pragma unroll
    for (int i = 0; i < 4; ++i)
      af[i] = *(const short8*)&Ab[(wr + i * 16 + l15) * 40 + lq * 8];
#pragma unroll
    for (int j = 0; j < 4; ++j)
      bfr[j] = *(const short8*)&Bb[(wc + j * 16 + l15) * 40 + lq * 8];
#pragma unroll
    for (int i = 0; i < 4; ++i)
#pragma unroll
      for (int j = 0; j < 4; ++j)
        acc[i][j] = __builtin_amdgcn_mfma_f32_16x16x32_bf16(af[i], bfr[j], acc[i][j], 0, 0, 0);
  }

  if (MODE == 1) {
    short* hb = (short*)outp;
    const float* bp = bias + (size_t)e * N + colbase;
#pragma unroll
    for (int i = 0; i < 4; ++i) {
      int rb = wr + i * 16 + lq * 4;
#pragma unroll
      for (int j = 0; j < 4; ++j) {
        int col = wc + j * 16 + l15;
        float bv = bp[col];
#pragma unroll
        for (int p = 0; p < 4; ++p) {
          int r = rb + p;
          if (r < vr)
            hb[(size_t)(lbuf + r) * HDIM + colbase + col] =
                (short)f2bf(gelu_fast(acc[i][j][p] + bv));
        }
      }
    }
  } else {
    float* y = (float*)outp;
    const float* bp = bias + (size_t)e * N + colbase;
#pragma unroll
    for (int i = 0; i < 4; ++i) {
      int rb = wr + i * 16 + lq * 4;
#pragma unroll
      for (int p = 0; p < 4; ++p) {
        int r = rb + p;
        if (r < vr) {
          int gi = r0 + rowbase + r;
          float g = slotgate[gi];
          float* yrow = y + (size_t)tokenlist[gi] * N + colbase;
#pragma unroll
          for (int j = 0; j < 4; ++j) {
            int col = wc + j * 16 + l15;
            float v = acc[i][j][p] + (split == 0 ? bp[col] : 0.f);
            atomicAdd(&yrow[col], g * v);
          }
        }
      }
    }
  }
}

extern "C" void kernel_launch(void* const* d_in, const int* in_sizes, int n_in,
                              void* d_out, int out_size, void* d_ws, size_t ws_size,
                              hipStream_t stream) {
  const float* x  = (const float*)d_in[0];
  const float* gw = (const float*)d_in[1];
  const float* w1 = (const float*)d_in[2];
  const float* b1 = (const float*)d_in[3];
  const float* w2 = (const float*)d_in[4];
  const float* b2 = (const float*)d_in[5];
  float* y = (float*)d_out;

  char* ws = (char*)d_ws;
  float* scores    = (float*)(ws);                    // 64 KB
  int*   tokenlist = (int*)(ws + (64 << 10));         // 16 KB
  float* slotgate  = (float*)(ws + (80 << 10));       // 16 KB
  int*   offsets   = (int*)(ws + (96 << 10));         // 9 ints
  int*   tilemap   = (int*)(ws + (96 << 10) + 256);   // 40 ints
  short* xbf       = (short*)(ws + (128 << 10));      // 3 MB
  short* hbuf      = (short*)(ws + (128 << 10) + (size_t)S_TOK * DDIM * 2);

  const size_t tile_bytes = (size_t)128 * HDIM * 2;   // 768 KB per 128-row tile
  size_t used = (size_t)(128 << 10) + (size_t)S_TOK * DDIM * 2;
  size_t avail = (ws_size > used) ? ws_size - used : 0;
  int tchunk = (int)(avail / tile_bytes);
  if (tchunk > NT_MAX) tchunk = NT_MAX;
  if (tchunk < 1) tchunk = 1;

  zero_kernel<<<(out_size + 255) / 256, 256, 0, stream>>>(y, out_size);
  convx_kernel<<<S_TOK * DDIM / 2048, 256, 0, stream>>>(x, xbf);
  gate_kernel<<<S_TOK / 4, 256, 0, stream>>>(x, gw, scores);
  select_kernel<<<1, 1024, 0, stream>>>(scores, tokenlist, slotgate, offsets, tilemap);

  for (int t0 = 0; t0 < NT_MAX; t0 += tchunk) {
    int tc = NT_MAX - t0; if (tc > tchunk) tc = tchunk;
    dim3 g1(HDIM / 128, tc, 1);
    moe_mfma<1><<<g1, 256, 0, stream>>>(xbf, w1, b1, hbuf, offsets, tokenlist,
                                        slotgate, tilemap, t0, DDIM, HDIM, DDIM);
    dim3 g2(DDIM / 128, tc, 2);
    moe_mfma<2><<<g2, 256, 0, stream>>>(hbuf, w2, b2, y, offsets, tokenlist,
                                        slotgate, tilemap, t0, HDIM, DDIM, HDIM / 2);
  }
}